// Round 10
// baseline (99.425 us; speedup 1.0000x reference)
//
#include <hip/hip_runtime.h>

typedef _Float16 half8 __attribute__((ext_vector_type(8)));
typedef float f32x4 __attribute__((ext_vector_type(4)));

#define NN 4096
#define NE 512
#define HD 64
#define KROWS 4288   // 64 pad + 4096 + 128 pad (per batch)
#define KOFF  64
#define WSCALE (1.0f / 256.0f)

// --- f16 helpers: RN hi + RN residual lo ---
__device__ __forceinline__ void f16_split(float f, _Float16& hi, _Float16& lo) {
    hi = (_Float16)f;                    // v_cvt_f16_f32 (RN)
    lo = (_Float16)(f - (float)hi);
}

#define MFMA16(a, b, c) __builtin_amdgcn_mfma_f32_16x16x32_f16((a), (b), (c), 0, 0, 0)

// ---------------------------------------------------------------------------
// prep: blocks 0..47  = wprep duties (W->B-frag f16; K pad zero; Vf init; Vs=0)
//       blocks 48..559 = xprep: x (fp32) -> A-frag-ordered f16 hi/lo.
// X frag layout: [rt(512)][kt(16)][lane(64)][j(8)], elem = x[rt*16+(L&15)]
//                [kt*32+(L>>4)*8+j].  Pure streaming (~25 MB traffic).
// ---------------------------------------------------------------------------
__global__ __launch_bounds__(256) void prep_kernel(
    const float* __restrict__ x,
    const float* __restrict__ Wq, const float* __restrict__ Wk,
    const float* __restrict__ Wv,
    _Float16* __restrict__ Wf, _Float16* __restrict__ Khi,
    _Float16* __restrict__ Vf, float* __restrict__ Vs,
    _Float16* __restrict__ Xfhi, _Float16* __restrict__ Xflo)
{
    const int blk = blockIdx.x;
    if (blk < 48) {
        const int gtid = blk * 256 + threadIdx.x;   // [0, 12288)
        const int L = gtid & 63;
        {
            const int nt = (gtid >> 6) % 12;
            const int kt = gtid / 768;
            const int n = nt * 16 + (L & 15);
            const int kbase = kt * 32 + (L >> 4) * 8;
            const float* src; int col;
            if (n < 64)       { src = Wq; col = n; }
            else if (n < 128) { src = Wk; col = n - 64; }
            else              { src = Wv; col = n - 128; }
            half8 sh;
#pragma unroll
            for (int j = 0; j < 8; ++j)
                sh[j] = (_Float16)src[(size_t)(kbase + j) * HD + col];
            *(half8*)(Wf + (size_t)gtid * 8) = sh;
        }
        if (gtid < 6144) {   // zero 768 K-pad rows x 128 B
            const int p = gtid >> 3, o = gtid & 7;
            const int b = p / 192, q = p - b * 192;
            const size_t row = (size_t)b * KROWS + (q < 64 ? q : 4096 + q);
            const half8 z = {0, 0, 0, 0, 0, 0, 0, 0};
            *(half8*)(Khi + row * HD + o * 8) = z;
        }
        if (gtid < 3200) {   // Vf init: zeros; nt==4 plane gets ones-pattern
            const int rem = gtid % 1600;
            const int jt = rem / 320;
            const int nt = (rem / 64) % 5;
            half8 sh = {0, 0, 0, 0, 0, 0, 0, 0};
            if (nt == 4 && (L & 15) == 0) {
#pragma unroll
                for (int jj = 0; jj < 8; ++jj) {
                    const int j = jt * 32 + (L >> 4) * 8 + jj;
                    if (j < 129) sh[jj] = (_Float16)1.0f;
                }
            }
            *(half8*)(Vf + (size_t)gtid * 8) = sh;
        }
        if (gtid < 128) Vs[gtid] = 0.f;
    } else {
        const int gt = (blk - 48) * 256 + threadIdx.x;   // [0, 131072)
#pragma unroll
        for (int i = 0; i < 4; ++i) {
            const int s = gt + i * 131072;               // slot [0, 524288)
            const int rt = s >> 10;
            const int kt = (s >> 6) & 15;
            const int L = s & 63;
            const int row = rt * 16 + (L & 15);
            const int k = kt * 32 + (L >> 4) * 8;
            const float4 x0 = *(const float4*)(x + (size_t)row * NE + k);
            const float4 x1 = *(const float4*)(x + (size_t)row * NE + k + 4);
            const float xv[8] = {x0.x, x0.y, x0.z, x0.w,
                                 x1.x, x1.y, x1.z, x1.w};
            half8 hh, ll;
#pragma unroll
            for (int j = 0; j < 8; ++j) {
                _Float16 h, l; f16_split(xv[j], h, l);
                hh[j] = h; ll[j] = l;
            }
            *(half8*)(Xfhi + (size_t)s * 8) = hh;
            *(half8*)(Xflo + (size_t)s * 8) = ll;
        }
    }
}

// ---------------------------------------------------------------------------
// proj: QKV = x @ W + b, 2-pass f16 MFMA. grid 512 x 256 (4 waves):
// block = 16-row tile (rt = blk), wave w owns ntiles 3w..3w+2.
// K-loop is now PURE 5 b128 loads + 6 MFMA per kt (x pre-split by prep) —
// zero VALU between loads, nothing for the compiler to serialize on.
// Epilogue: Q f16 hi+lo row-major, K f16 hi, V -> LDS -> Vsum + V-frags.
// ---------------------------------------------------------------------------
__global__ __launch_bounds__(256) void proj_kernel(
    const _Float16* __restrict__ Xfhi, const _Float16* __restrict__ Xflo,
    const _Float16* __restrict__ Wf,
    const float* __restrict__ bq, const float* __restrict__ bk,
    const float* __restrict__ bv,
    _Float16* __restrict__ Qhi, _Float16* __restrict__ Qlo,
    _Float16* __restrict__ Khi, _Float16* __restrict__ Vf,
    float* __restrict__ Vs)
{
    __shared__ float V_lds[16][68];
    const int tid = threadIdx.x;
    const int L = tid & 63;
    const int w = tid >> 6;              // wave 0..3
    const int m = L & 15, kg = L >> 4;
    const int blk = blockIdx.x;          // rt
    const int r0 = blk * 16;
    const int b = blk >> 8;

    f32x4 acc[3];
#pragma unroll
    for (int t = 0; t < 3; ++t) acc[t] = (f32x4){0.f, 0.f, 0.f, 0.f};

    const _Float16* xf = Xfhi + ((size_t)blk * 16 * 64 + L) * 8;
    const _Float16* xl = Xflo + ((size_t)blk * 16 * 64 + L) * 8;
    const _Float16* wf = Wf + ((size_t)(w * 3) * 64 + L) * 8;

#pragma unroll
    for (int kt = 0; kt < 16; ++kt) {
        const half8 ahi = *(const half8*)(xf + (size_t)kt * 512);
        const half8 alo = *(const half8*)(xl + (size_t)kt * 512);
#pragma unroll
        for (int t = 0; t < 3; ++t) {
            const half8 wv = *(const half8*)(wf + ((size_t)kt * 12 + t) * 512);
            acc[t] = MFMA16(ahi, wv, acc[t]);
            acc[t] = MFMA16(alo, wv, acc[t]);
        }
    }

    // ---- epilogue: Q/K stores, V -> LDS ----
#pragma unroll
    for (int t = 0; t < 3; ++t) {
        const int nt = w * 3 + t;
        const int cgc = nt * 16 + m;     // global col 0..191
        const float bias = (cgc < 64) ? bq[cgc]
                         : (cgc < 128) ? bk[cgc - 64] : bv[cgc - 128];
#pragma unroll
        for (int r = 0; r < 4; ++r) {
            const int gr = r0 + kg * 4 + r;
            const float val = acc[t][r] + bias;
            if (cgc < 64) {
                _Float16 hh, ll; f16_split(val, hh, ll);
                Qhi[(size_t)gr * HD + cgc] = hh;
                Qlo[(size_t)gr * HD + cgc] = ll;
            } else if (cgc < 128) {
                const int d = cgc - 64, n = gr & 4095;
                Khi[((size_t)b * KROWS + KOFF + n) * HD + d] = (_Float16)val;
            } else {
                V_lds[kg * 4 + r][cgc - 128] = val;
            }
        }
    }
    __syncthreads();

    // Vsum: one atomic per dim
    if (tid < 64) {
        float s = 0.f;
#pragma unroll
        for (int r = 0; r < 16; ++r) s += V_lds[r][tid];
        atomicAdd(&Vs[b * HD + tid], s);
    }

    // V-frag emission for rows < 129 (16-row blocks: local 0..7 -> two
    // kg-chunks of jt=local>>1; local 8 -> j==128 only).
    {
        const int local = blk & 255;
        if (local < 8) {
            const int jt = local >> 1;
            if ((kg >> 1) == (local & 1)) {   // this block owns this kg pair
                const int nt = w;             // V ntile 0..3
                half8 sh;
#pragma unroll
                for (int jj = 0; jj < 8; ++jj) {
                    const int lrow = (kg - (local & 1) * 2) * 8 + jj;  // 0..15
                    sh[jj] = (_Float16)V_lds[lrow][nt * 16 + m];
                }
                const size_t fo = ((size_t)((b * 25 + jt * 5 + nt) * 64 + L)) * 8;
                *(half8*)(Vf + fo) = sh;
            }
        } else if (local == 8 && kg == 0) {
            const int nt = w;
            half8 sh = {0, 0, 0, 0, 0, 0, 0, 0};
            sh[0] = (_Float16)V_lds[0][nt * 16 + m];   // j == 128
            const size_t fo = ((size_t)((b * 25 + 4 * 5 + nt) * 64 + L)) * 8;
            *(half8*)(Vf + fo) = sh;
        }
    }
}

// ---------------------------------------------------------------------------
// attn: grid 512 (b = blk>>8, 16 queries/block), block 256 (4 waves).
// f16 2-pass, all global loads upfront. Phase 1: S = (qhi+qlo).Khi^T,
// w' = (exp(s)-1)/256 -> LDS f16 hi/lo. Phase 2: [out|den] = wt @ [V|1|0];
// wave wv owns ntile wv; wave 0 also the ones-column tile. (Verbatim R9.)
// ---------------------------------------------------------------------------
__global__ __launch_bounds__(256) void attn_kernel(
    const _Float16* __restrict__ Qhi, const _Float16* __restrict__ Qlo,
    const _Float16* __restrict__ Khi, const _Float16* __restrict__ Vf,
    const float* __restrict__ Vs, float* __restrict__ out)
{
    __shared__ __align__(16) _Float16 wt_hi[16 * 168];
    __shared__ __align__(16) _Float16 wt_lo[16 * 168];
    __shared__ float den_lds[16];

    const int tid = threadIdx.x;
    const int L = tid & 63;
    const int w = tid >> 6;
    const int m = L & 15, kg = L >> 4;
    const int b = blockIdx.x >> 8;
    const int n0 = (blockIdx.x & 255) * 16;

    // ---- upfront load issuance (all independent) ----
    const _Float16* qp  = Qhi + ((size_t)(b * NN + n0 + m)) * HD + kg * 8;
    const _Float16* qp2 = Qlo + ((size_t)(b * NN + n0 + m)) * HD + kg * 8;
    const half8 qhi0 = *(const half8*)(qp);
    const half8 qhi1 = *(const half8*)(qp + 32);
    const half8 qlo0 = *(const half8*)(qp2);
    const half8 qlo1 = *(const half8*)(qp2 + 32);

    int kts[3]; int nkt;
    if (w == 3) { kts[0] = 3; kts[1] = 7; kts[2] = 8; nkt = 3; }
    else        { kts[0] = w; kts[1] = w + 4; kts[2] = 0; nkt = 2; }

    const _Float16* KB = Khi + (size_t)b * KROWS * HD;
    half8 kh0[3], kh1[3];
#pragma unroll
    for (int i = 0; i < 3; ++i) {
        if (i < nkt) {                   // wave-uniform branch
            const _Float16* kp = KB + (size_t)(n0 + kts[i] * 16 + m) * HD + kg * 8;
            kh0[i] = *(const half8*)(kp);
            kh1[i] = *(const half8*)(kp + 32);
        }
    }

    half8 vhi[5], vh4[5];
#pragma unroll
    for (int jt = 0; jt < 5; ++jt) {
        const size_t fo = ((size_t)((b * 25 + jt * 5 + w) * 64 + L)) * 8;
        vhi[jt] = *(const half8*)(Vf + fo);
    }
    if (w == 0) {                        // wave-uniform
#pragma unroll
        for (int jt = 0; jt < 5; ++jt) {
            const size_t fo4 = ((size_t)((b * 25 + jt * 5 + 4) * 64 + L)) * 8;
            vh4[jt] = *(const half8*)(Vf + fo4);
        }
    }

    // zero the (q,j) weight buffer (j in [129,168) must read as 0)
    for (int i = tid; i < (16 * 168) / 2; i += 256) {
        ((int*)wt_hi)[i] = 0;
        ((int*)wt_lo)[i] = 0;
    }
    __syncthreads();

    // ---- phase 1 ----
#pragma unroll
    for (int i = 0; i < 3; ++i) {
        if (i < nkt) {
            f32x4 acc = (f32x4){0.f, 0.f, 0.f, 0.f};
            acc = MFMA16(qhi0, kh0[i], acc);
            acc = MFMA16(qhi1, kh1[i], acc);
            acc = MFMA16(qlo0, kh0[i], acc);
            acc = MFMA16(qlo1, kh1[i], acc);
            const int l = kts[i] * 16 + m;
#pragma unroll
            for (int r = 0; r < 4; ++r) {
                const int q = kg * 4 + r;
                const int j = l - q;
                if (j >= 0 && j < 129) {
                    const float wval = (__expf(acc[r]) - 1.0f) * WSCALE;
                    _Float16 hh, ll; f16_split(wval, hh, ll);
                    wt_hi[q * 168 + j] = hh;
                    wt_lo[q * 168 + j] = ll;
                }
            }
        }
    }
    __syncthreads();

    // ---- phase 2 ----
    f32x4 oacc = (f32x4){0.f, 0.f, 0.f, 0.f};
    f32x4 dacc = (f32x4){0.f, 0.f, 0.f, 0.f};
#pragma unroll
    for (int jt = 0; jt < 5; ++jt) {
        const half8 whi = *(const half8*)(wt_hi + m * 168 + jt * 32 + kg * 8);
        const half8 wlo = *(const half8*)(wt_lo + m * 168 + jt * 32 + kg * 8);
        oacc = MFMA16(whi, vhi[jt], oacc);
        oacc = MFMA16(wlo, vhi[jt], oacc);
        if (w == 0) {
            dacc = MFMA16(whi, vh4[jt], dacc);
            dacc = MFMA16(wlo, vh4[jt], dacc);
        }
    }
    if (w == 0 && m == 0) {
#pragma unroll
        for (int r = 0; r < 4; ++r) den_lds[kg * 4 + r] = dacc[r];
    }
    __syncthreads();

    // ---- epilogue (unscale: num = 256*oacc, den = 4096 + 256*dacc) ----
    {
        const float vs = Vs[b * HD + w * 16 + m];
#pragma unroll
        for (int r = 0; r < 4; ++r) {
            const int q = kg * 4 + r;
            const float val = (vs + 256.0f * oacc[r])
                            / (4096.f + 256.0f * den_lds[q]);
            out[((size_t)(b * NN + n0 + q)) * HD + w * 16 + m] = val;
        }
    }
}

// ---------------------------------------------------------------------------
extern "C" void kernel_launch(void* const* d_in, const int* in_sizes, int n_in,
                              void* d_out, int out_size, void* d_ws, size_t ws_size,
                              hipStream_t stream)
{
    const float* x  = (const float*)d_in[0];
    const float* Wq = (const float*)d_in[1];
    const float* bq = (const float*)d_in[2];
    const float* Wk = (const float*)d_in[3];
    const float* bk = (const float*)d_in[4];
    const float* Wv = (const float*)d_in[5];
    const float* bv = (const float*)d_in[6];
    float* out = (float*)d_out;

    char* ws = (char*)d_ws;
    float*     Vs   = (float*)(ws + 0);              //      512 B
    _Float16*  Khi  = (_Float16*)(ws + 512);         // 1097728 B
    _Float16*  Qhi  = (_Float16*)(ws + 1098240);     // 1048576 B
    _Float16*  Qlo  = (_Float16*)(ws + 2146816);     // 1048576 B
    _Float16*  Wf   = (_Float16*)(ws + 3195392);     //  196608 B
    _Float16*  Vf   = (_Float16*)(ws + 3392000);     //   51200 B
    _Float16*  Xfhi = (_Float16*)(ws + 3443200);     // 8388608 B
    _Float16*  Xflo = (_Float16*)(ws + 11831808);    // 8388608 B

    prep_kernel<<<560, 256, 0, stream>>>(x, Wq, Wk, Wv, Wf, Khi, Vf, Vs,
                                         Xfhi, Xflo);
    proj_kernel<<<512, 256, 0, stream>>>(Xfhi, Xflo, Wf, bq, bk, bv,
                                         Qhi, Qlo, Khi, Vf, Vs);
    attn_kernel<<<512, 256, 0, stream>>>(Qhi, Qlo, Khi, Vf, Vs, out);
}